// Round 2
// baseline (309.859 us; speedup 1.0000x reference)
//
#include <hip/hip_runtime.h>
#include <hip/hip_bf16.h>

typedef __hip_bfloat16 bf16;
typedef __attribute__((ext_vector_type(8))) short bfrag;   // 8 x bf16 (4 VGPRs)
typedef __attribute__((ext_vector_type(4))) float f32x4;

#define MFMA(a,b,c) __builtin_amdgcn_mfma_f32_16x16x32_bf16((a),(b),(c),0,0,0)

__device__ __forceinline__ float b2f(bf16 x){ return __bfloat162float(x); }
__device__ __forceinline__ bf16 f2b(float x){ return __float2bfloat16(x); }

#define NN  3136   // 56*56, divisible by 64
#define NBH 8      // B * NH

// ---------------- Kernel 0: QKV 1x1 conv projections (f32 in -> bf16 staged) ----------------
// kt: [bh][N][32] row-major (bf16), qt: [bh][N][32], vt: [bh][32][N]
__global__ __launch_bounds__(256) void k_proj(
    const float* __restrict__ x,
    const float* __restrict__ wk, const float* __restrict__ bk,
    const float* __restrict__ wq, const float* __restrict__ bq,
    const float* __restrict__ wv, const float* __restrict__ bv,
    bf16* __restrict__ kt, bf16* __restrict__ qt, bf16* __restrict__ vt)
{
    int n = blockIdx.x * 256 + threadIdx.x;
    if (n >= NN) return;
    int oc = blockIdx.y;            // 0..127
    int z  = blockIdx.z;            // 0..5
    int b = z & 1, proj = z >> 1;   // proj: 0=k,1=q,2=v
    const float* w    = (proj == 0) ? wk : ((proj == 1) ? wq : wv);
    const float* bias = (proj == 0) ? bk : ((proj == 1) ? bq : bv);
    float sum = bias[oc];
    const float* xp = x + (size_t)b * 64 * NN + n;
    const float* wp = w + oc * 64;
    #pragma unroll 8
    for (int c = 0; c < 64; ++c)
        sum += wp[c] * xp[(size_t)c * NN];
    int h = oc >> 5, d = oc & 31;
    size_t bh = (size_t)b * 4 + h;
    bf16 v = f2b(sum);
    if (proj == 0)      kt[(bh * NN + n) * 32 + d] = v;
    else if (proj == 1) qt[(bh * NN + n) * 32 + d] = v;
    else                vt[(bh * 32 + d) * NN + n] = v;
}

// ---------------- Kernel A: column softmax denominators ----------------
// rden[bh][m] = 1 / sum_n exp(S[n,m]);  S = Kt @ Qt^T (K=32, one MFMA per tile)
__global__ __launch_bounds__(256) void k_stats(const bf16* __restrict__ kt,
                                               const bf16* __restrict__ qt,
                                               float* __restrict__ rden)
{
    __shared__ float red[256];
    int bh = blockIdx.y;
    int m0 = blockIdx.x * 64;
    int tid = threadIdx.x;
    int w = tid >> 6, lane = tid & 63;
    int l15 = lane & 15, lhi = lane >> 4;

    bfrag qb[4];
    #pragma unroll
    for (int t = 0; t < 4; ++t)
        qb[t] = *reinterpret_cast<const bfrag*>(qt + ((size_t)bh * NN + m0 + 16 * t + l15) * 32 + lhi * 8);

    float vsum[4] = {0.f, 0.f, 0.f, 0.f};
    for (int nb = 0; nb < NN; nb += 64) {
        bfrag a = *reinterpret_cast<const bfrag*>(kt + ((size_t)bh * NN + nb + w * 16 + l15) * 32 + lhi * 8);
        #pragma unroll
        for (int t = 0; t < 4; ++t) {
            f32x4 d = {0.f, 0.f, 0.f, 0.f};
            d = MFMA(a, qb[t], d);
            vsum[t] += __expf(d[0]) + __expf(d[1]) + __expf(d[2]) + __expf(d[3]);
        }
    }
    #pragma unroll
    for (int t = 0; t < 4; ++t) {
        vsum[t] += __shfl_xor(vsum[t], 16);
        vsum[t] += __shfl_xor(vsum[t], 32);
    }
    if (lane < 16) {
        #pragma unroll
        for (int t = 0; t < 4; ++t) red[w * 64 + 16 * t + lane] = vsum[t];
    }
    __syncthreads();
    if (tid < 64) {
        float s = red[tid] + red[64 + tid] + red[128 + tid] + red[192 + tid];
        rden[(size_t)bh * NN + m0 + tid] = 1.0f / s;
    }
}

// ---------------- Kernel B: av = P @ V, then avw = relu(bn1(av@w1^T+b1)) ----------------
// writes awts[bh][64(e)][N] = avw^T (bf16)
__global__ __launch_bounds__(256) void k_av(const bf16* __restrict__ kt,
    const bf16* __restrict__ qt, const bf16* __restrict__ vt,
    const float* __restrict__ rden,
    const float* __restrict__ w1, const float* __restrict__ b1,
    const float* __restrict__ g1, const float* __restrict__ be1,
    const float* __restrict__ rm1, const float* __restrict__ rv1,
    bf16* __restrict__ awts)
{
    __shared__ __align__(16) bf16 p_lds[64 * 72];
    __shared__ float av_lds[64 * 33];
    __shared__ float w1_lds[64 * 32];
    __shared__ float s1_lds[64], sh1_lds[64], b1_lds[64];

    int bh = blockIdx.y, h = bh & 3;
    int n0 = blockIdx.x * 64;
    int tid = threadIdx.x;
    int w = tid >> 6, lane = tid & 63;
    int l15 = lane & 15, lhi = lane >> 4;

    for (int i = tid; i < 64 * 32; i += 256) w1_lds[i] = w1[i];
    if (tid < 64) {
        int ch = h * 64 + tid;
        float sc = g1[ch] * rsqrtf(rv1[ch] + 1e-5f);
        s1_lds[tid]  = sc;
        sh1_lds[tid] = be1[ch] - rm1[ch] * sc;
        b1_lds[tid]  = b1[tid];
    }

    const float* rdp = rden + (size_t)bh * NN;
    bfrag ak = *reinterpret_cast<const bfrag*>(kt + ((size_t)bh * NN + n0 + w * 16 + l15) * 32 + lhi * 8);

    f32x4 acc0 = {0.f, 0.f, 0.f, 0.f}, acc1 = {0.f, 0.f, 0.f, 0.f};
    int rowb = w * 16 + lhi * 4;

    for (int mb = 0; mb < NN; mb += 64) {
        #pragma unroll
        for (int t = 0; t < 4; ++t) {
            bfrag qb = *reinterpret_cast<const bfrag*>(qt + ((size_t)bh * NN + mb + 16 * t + l15) * 32 + lhi * 8);
            f32x4 d = {0.f, 0.f, 0.f, 0.f};
            d = MFMA(ak, qb, d);
            float rd = rdp[mb + 16 * t + l15];
            int colb = 16 * t + l15;
            p_lds[(rowb + 0) * 72 + colb] = f2b(__expf(d[0]) * rd);
            p_lds[(rowb + 1) * 72 + colb] = f2b(__expf(d[1]) * rd);
            p_lds[(rowb + 2) * 72 + colb] = f2b(__expf(d[2]) * rd);
            p_lds[(rowb + 3) * 72 + colb] = f2b(__expf(d[3]) * rd);
        }
        __syncthreads();
        #pragma unroll
        for (int s = 0; s < 2; ++s) {
            bfrag ap = *reinterpret_cast<const bfrag*>(&p_lds[(w * 16 + l15) * 72 + s * 32 + lhi * 8]);
            bfrag vb0 = *reinterpret_cast<const bfrag*>(vt + ((size_t)bh * 32 + 0  + l15) * NN + mb + s * 32 + lhi * 8);
            bfrag vb1 = *reinterpret_cast<const bfrag*>(vt + ((size_t)bh * 32 + 16 + l15) * NN + mb + s * 32 + lhi * 8);
            acc0 = MFMA(ap, vb0, acc0);
            acc1 = MFMA(ap, vb1, acc1);
        }
        __syncthreads();
    }
    #pragma unroll
    for (int r = 0; r < 4; ++r) {
        av_lds[(rowb + r) * 33 + l15]      = acc0[r];
        av_lds[(rowb + r) * 33 + 16 + l15] = acc1[r];
    }
    __syncthreads();
    for (int idx = tid; idx < 64 * 64; idx += 256) {
        int nl = idx & 63, e = idx >> 6;
        float sum = b1_lds[e];
        #pragma unroll 8
        for (int d = 0; d < 32; ++d) sum += av_lds[nl * 33 + d] * w1_lds[e * 32 + d];
        float v = fmaxf(sum * s1_lds[e] + sh1_lds[e], 0.f);
        awts[((size_t)bh * 64 + e) * NN + n0 + nl] = f2b(v);
    }
}

// ---------------- Kernel C: av2 = P @ avw, avw2 = relu(bn2(av2@w2^T+b2)) ----------------
// writes y[b][256(h*64+e)][N] (bf16)
__global__ __launch_bounds__(256) void k_av2(const bf16* __restrict__ kt,
    const bf16* __restrict__ qt, const float* __restrict__ rden,
    const bf16* __restrict__ awts,
    const float* __restrict__ w2, const float* __restrict__ b2,
    const float* __restrict__ g2, const float* __restrict__ be2,
    const float* __restrict__ rm2, const float* __restrict__ rv2,
    bf16* __restrict__ y)
{
    __shared__ __align__(16) bf16 p_lds[64 * 72];
    __shared__ float a2_lds[64 * 65];
    __shared__ float w2_lds[64 * 64];
    __shared__ float s2_lds[64], sh2_lds[64], b2_lds[64];

    int bh = blockIdx.y, h = bh & 3, b = bh >> 2;
    int n0 = blockIdx.x * 64;
    int tid = threadIdx.x;
    int w = tid >> 6, lane = tid & 63;
    int l15 = lane & 15, lhi = lane >> 4;

    for (int i = tid; i < 64 * 64; i += 256) w2_lds[i] = w2[i];
    if (tid < 64) {
        int ch = h * 64 + tid;
        float sc = g2[ch] * rsqrtf(rv2[ch] + 1e-5f);
        s2_lds[tid]  = sc;
        sh2_lds[tid] = be2[ch] - rm2[ch] * sc;
        b2_lds[tid]  = b2[tid];
    }

    const float* rdp = rden + (size_t)bh * NN;
    bfrag ak = *reinterpret_cast<const bfrag*>(kt + ((size_t)bh * NN + n0 + w * 16 + l15) * 32 + lhi * 8);

    f32x4 acc[4];
    #pragma unroll
    for (int et = 0; et < 4; ++et) { acc[et][0]=0.f; acc[et][1]=0.f; acc[et][2]=0.f; acc[et][3]=0.f; }
    int rowb = w * 16 + lhi * 4;

    for (int mb = 0; mb < NN; mb += 64) {
        #pragma unroll
        for (int t = 0; t < 4; ++t) {
            bfrag qb = *reinterpret_cast<const bfrag*>(qt + ((size_t)bh * NN + mb + 16 * t + l15) * 32 + lhi * 8);
            f32x4 d = {0.f, 0.f, 0.f, 0.f};
            d = MFMA(ak, qb, d);
            float rd = rdp[mb + 16 * t + l15];
            int colb = 16 * t + l15;
            p_lds[(rowb + 0) * 72 + colb] = f2b(__expf(d[0]) * rd);
            p_lds[(rowb + 1) * 72 + colb] = f2b(__expf(d[1]) * rd);
            p_lds[(rowb + 2) * 72 + colb] = f2b(__expf(d[2]) * rd);
            p_lds[(rowb + 3) * 72 + colb] = f2b(__expf(d[3]) * rd);
        }
        __syncthreads();
        #pragma unroll
        for (int s = 0; s < 2; ++s) {
            bfrag ap = *reinterpret_cast<const bfrag*>(&p_lds[(w * 16 + l15) * 72 + s * 32 + lhi * 8]);
            #pragma unroll
            for (int et = 0; et < 4; ++et) {
                bfrag ab = *reinterpret_cast<const bfrag*>(awts + ((size_t)bh * 64 + et * 16 + l15) * NN + mb + s * 32 + lhi * 8);
                acc[et] = MFMA(ap, ab, acc[et]);
            }
        }
        __syncthreads();
    }
    #pragma unroll
    for (int et = 0; et < 4; ++et)
        #pragma unroll
        for (int r = 0; r < 4; ++r)
            a2_lds[(rowb + r) * 65 + et * 16 + l15] = acc[et][r];
    __syncthreads();
    for (int idx = tid; idx < 64 * 64; idx += 256) {
        int nl = idx & 63, e = idx >> 6;
        float sum = b2_lds[e];
        #pragma unroll 8
        for (int d = 0; d < 64; ++d) sum += a2_lds[nl * 65 + d] * w2_lds[e * 64 + d];
        float v = fmaxf(sum * s2_lds[e] + sh2_lds[e], 0.f);
        y[((size_t)b * 256 + h * 64 + e) * NN + n0 + nl] = f2b(v);
    }
}

// ---------------- Kernel D: final 1x1 conv (f32 out) ----------------
__global__ __launch_bounds__(256) void k_final(const bf16* __restrict__ y,
    const float* __restrict__ wf, const float* __restrict__ bf_,
    float* __restrict__ out)
{
    int n = blockIdx.x * 256 + threadIdx.x;
    if (n >= NN) return;
    int o = blockIdx.y;
    int b = blockIdx.z;
    float sum = bf_[o];
    const bf16* yp = y + (size_t)b * 256 * NN + n;
    const float* wp = wf + o * 256;
    #pragma unroll 8
    for (int k = 0; k < 256; ++k)
        sum += wp[k] * b2f(yp[(size_t)k * NN]);
    out[((size_t)b * 64 + o) * NN + n] = sum;
}

extern "C" void kernel_launch(void* const* d_in, const int* in_sizes, int n_in,
                              void* d_out, int out_size, void* d_ws, size_t ws_size,
                              hipStream_t stream)
{
    const float* x   = (const float*)d_in[0];
    const float* wk  = (const float*)d_in[1];
    const float* bk  = (const float*)d_in[2];
    const float* wq  = (const float*)d_in[3];
    const float* bq  = (const float*)d_in[4];
    const float* wv  = (const float*)d_in[5];
    const float* bv  = (const float*)d_in[6];
    const float* w1  = (const float*)d_in[7];
    const float* b1  = (const float*)d_in[8];
    const float* g1  = (const float*)d_in[9];
    const float* be1 = (const float*)d_in[10];
    const float* rm1 = (const float*)d_in[11];
    const float* rv1 = (const float*)d_in[12];
    const float* w2  = (const float*)d_in[13];
    const float* b2  = (const float*)d_in[14];
    const float* g2  = (const float*)d_in[15];
    const float* be2 = (const float*)d_in[16];
    const float* rm2 = (const float*)d_in[17];
    const float* rv2 = (const float*)d_in[18];
    const float* wf  = (const float*)d_in[19];
    const float* bff = (const float*)d_in[20];
    float* out = (float*)d_out;

    char* ws = (char*)d_ws;
    bf16* kt = (bf16*)ws;                              // 8*3136*32 bf16
    bf16* qt = kt + (size_t)NBH * NN * 32;
    bf16* vt = qt + (size_t)NBH * NN * 32;
    float* rden = (float*)(vt + (size_t)NBH * 32 * NN);
    bf16* awts = (bf16*)(rden + (size_t)NBH * NN);     // 8*64*3136 bf16
    bf16* y = awts + (size_t)NBH * 64 * NN;            // 2*256*3136 bf16

    k_proj <<<dim3(13, 128, 6), 256, 0, stream>>>(x, wk, bk, wq, bq, wv, bv, kt, qt, vt);
    k_stats<<<dim3(49, 8),      256, 0, stream>>>(kt, qt, rden);
    k_av   <<<dim3(49, 8),      256, 0, stream>>>(kt, qt, vt, rden, w1, b1, g1, be1, rm1, rv1, awts);
    k_av2  <<<dim3(49, 8),      256, 0, stream>>>(kt, qt, rden, awts, w2, b2, g2, be2, rm2, rv2, y);
    k_final<<<dim3(13, 64, 2),  256, 0, stream>>>(y, wf, bff, out);
}

// Round 3
// 261.160 us; speedup vs baseline: 1.1865x; 1.1865x over previous
//
#include <hip/hip_runtime.h>
#include <hip/hip_bf16.h>

typedef __hip_bfloat16 bf16;
typedef __attribute__((ext_vector_type(8))) short bfrag;   // 8 x bf16 (4 VGPRs)
typedef __attribute__((ext_vector_type(4))) float f32x4;

#define MFMA(a,b,c) __builtin_amdgcn_mfma_f32_16x16x32_bf16((a),(b),(c),0,0,0)

__device__ __forceinline__ float b2f(bf16 x){ return __bfloat162float(x); }
__device__ __forceinline__ bf16 f2b(float x){ return __float2bfloat16(x); }

#define NN   3136   // 56*56
#define NBH  8      // B * NH
#define MCH  448    // m/n chunk = 7 tiles of 64

// ---------------- zero accumulators (den + av_acc + av2_acc, contiguous f32) ----------------
__global__ __launch_bounds__(256) void k_zero(float* __restrict__ p, int n4)
{
    int i = blockIdx.x * 256 + threadIdx.x;
    if (i < n4) reinterpret_cast<f32x4*>(p)[i] = (f32x4){0.f, 0.f, 0.f, 0.f};
}

// ---------------- QKV 1x1 conv projections, LDS-tiled ----------------
// kt: [bh][N][32], qt: [bh][N][32], vt: [bh][32][N]   (bf16)
__global__ __launch_bounds__(256) void k_proj(
    const float* __restrict__ x,
    const float* __restrict__ wk, const float* __restrict__ bk,
    const float* __restrict__ wq, const float* __restrict__ bq,
    const float* __restrict__ wv, const float* __restrict__ bv,
    bf16* __restrict__ kt, bf16* __restrict__ qt, bf16* __restrict__ vt)
{
    __shared__ float xl[64 * 65];
    __shared__ float wl[96 * 64];
    __shared__ float bl[96];
    int n0 = blockIdx.x * 64;
    int b  = blockIdx.y;
    int z  = blockIdx.z;           // channel quarter: 96 of 384 (proj,oc) pairs
    int tid = threadIdx.x;

    for (int i = tid; i < 4096; i += 256) {
        int c = i >> 6, n = i & 63;
        xl[c * 65 + n] = x[((size_t)b * 64 + c) * NN + n0 + n];
    }
    const float* wp_[3] = {wk, wq, wv};
    const float* bp_[3] = {bk, bq, bv};
    for (int i = tid; i < 96 * 64; i += 256) {
        int j = i >> 6, c = i & 63;
        int ch = z * 96 + j, pr = ch >> 7, oc = ch & 127;
        wl[i] = wp_[pr][oc * 64 + c];
    }
    if (tid < 96) { int ch = z * 96 + tid; bl[tid] = bp_[ch >> 7][ch & 127]; }
    __syncthreads();

    int n = tid & 63, jg = tid >> 6;   // jg uniform per wave
    for (int j0 = jg * 24; j0 < (jg + 1) * 24; j0 += 4) {
        float s0 = bl[j0+0], s1 = bl[j0+1], s2 = bl[j0+2], s3 = bl[j0+3];
        for (int c = 0; c < 64; ++c) {
            float xv = xl[c * 65 + n];
            s0 += xv * wl[(j0+0) * 64 + c];
            s1 += xv * wl[(j0+1) * 64 + c];
            s2 += xv * wl[(j0+2) * 64 + c];
            s3 += xv * wl[(j0+3) * 64 + c];
        }
        float sv[4] = {s0, s1, s2, s3};
        #pragma unroll
        for (int q = 0; q < 4; ++q) {
            int ch = z * 96 + j0 + q;
            int pr = ch >> 7, oc = ch & 127, h = oc >> 5, d = oc & 31;
            size_t bh = (size_t)b * 4 + h;
            bf16 v = f2b(sv[q]);
            if (pr == 0)      kt[(bh * NN + n0 + n) * 32 + d] = v;
            else if (pr == 1) qt[(bh * NN + n0 + n) * 32 + d] = v;
            else              vt[(bh * 32 + d) * NN + n0 + n] = v;
        }
    }
}

// ---------------- column softmax denominators (split-n, atomic) ----------------
__global__ __launch_bounds__(256) void k_stats(const bf16* __restrict__ kt,
                                               const bf16* __restrict__ qt,
                                               float* __restrict__ den)
{
    __shared__ float red[256];
    int bh = blockIdx.z;
    int m0 = blockIdx.x * 64;
    int ns = blockIdx.y * MCH;
    int tid = threadIdx.x;
    int w = tid >> 6, lane = tid & 63;
    int l15 = lane & 15, lhi = lane >> 4;

    bfrag qb[4];
    #pragma unroll
    for (int t = 0; t < 4; ++t)
        qb[t] = *reinterpret_cast<const bfrag*>(qt + ((size_t)bh * NN + m0 + 16 * t + l15) * 32 + lhi * 8);

    float vsum[4] = {0.f, 0.f, 0.f, 0.f};
    for (int nb = ns; nb < ns + MCH; nb += 64) {
        bfrag a = *reinterpret_cast<const bfrag*>(kt + ((size_t)bh * NN + nb + w * 16 + l15) * 32 + lhi * 8);
        #pragma unroll
        for (int t = 0; t < 4; ++t) {
            f32x4 d = {0.f, 0.f, 0.f, 0.f};
            d = MFMA(a, qb[t], d);
            vsum[t] += __expf(d[0]) + __expf(d[1]) + __expf(d[2]) + __expf(d[3]);
        }
    }
    #pragma unroll
    for (int t = 0; t < 4; ++t) {
        vsum[t] += __shfl_xor(vsum[t], 16);
        vsum[t] += __shfl_xor(vsum[t], 32);
    }
    if (lane < 16) {
        #pragma unroll
        for (int t = 0; t < 4; ++t) red[w * 64 + 16 * t + lane] = vsum[t];
    }
    __syncthreads();
    if (tid < 64) {
        float s = red[tid] + red[64 + tid] + red[128 + tid] + red[192 + tid];
        atomicAdd(&den[(size_t)bh * NN + m0 + tid], s);
    }
}

__global__ __launch_bounds__(256) void k_recip(float* __restrict__ den)
{
    int i = blockIdx.x * 256 + threadIdx.x;
    if (i < NBH * NN) den[i] = 1.0f / den[i];
}

// ---------------- av partial: split-K over m, barrier-free, atomic f32 ----------------
__global__ __launch_bounds__(256) void k_av(const bf16* __restrict__ kt,
    const bf16* __restrict__ qt, const bf16* __restrict__ vt,
    const float* __restrict__ rden, float* __restrict__ av_acc)
{
    __shared__ __align__(16) bf16 p_lds[2][64 * 72];
    int bh = blockIdx.z;
    int n0 = blockIdx.x * 64;
    int ms = blockIdx.y * MCH;
    int tid = threadIdx.x;
    int w = tid >> 6, lane = tid & 63, l15 = lane & 15, lhi = lane >> 4;
    const float* rdp = rden + (size_t)bh * NN;

    bfrag ak = *reinterpret_cast<const bfrag*>(kt + ((size_t)bh * NN + n0 + w * 16 + l15) * 32 + lhi * 8);
    f32x4 acc0 = {0.f,0.f,0.f,0.f}, acc1 = {0.f,0.f,0.f,0.f};
    int rowb = w * 16 + lhi * 4;

    for (int mb = ms; mb < ms + MCH; mb += 64) {
        bf16* pb = p_lds[(mb >> 6) & 1];
        #pragma unroll
        for (int t = 0; t < 4; ++t) {
            bfrag qb = *reinterpret_cast<const bfrag*>(qt + ((size_t)bh * NN + mb + 16 * t + l15) * 32 + lhi * 8);
            f32x4 d = {0.f,0.f,0.f,0.f};
            d = MFMA(ak, qb, d);
            float rd = rdp[mb + 16 * t + l15];
            int colb = 16 * t + l15;
            pb[(rowb + 0) * 72 + colb] = f2b(__expf(d[0]) * rd);
            pb[(rowb + 1) * 72 + colb] = f2b(__expf(d[1]) * rd);
            pb[(rowb + 2) * 72 + colb] = f2b(__expf(d[2]) * rd);
            pb[(rowb + 3) * 72 + colb] = f2b(__expf(d[3]) * rd);
        }
        // wave-private P rows: no barrier needed
        #pragma unroll
        for (int s = 0; s < 2; ++s) {
            bfrag ap  = *reinterpret_cast<const bfrag*>(&pb[(w * 16 + l15) * 72 + s * 32 + lhi * 8]);
            bfrag vb0 = *reinterpret_cast<const bfrag*>(vt + ((size_t)bh * 32 + l15) * NN + mb + s * 32 + lhi * 8);
            bfrag vb1 = *reinterpret_cast<const bfrag*>(vt + ((size_t)bh * 32 + 16 + l15) * NN + mb + s * 32 + lhi * 8);
            acc0 = MFMA(ap, vb0, acc0);
            acc1 = MFMA(ap, vb1, acc1);
        }
    }
    float* dst = av_acc + ((size_t)bh * NN + n0 + rowb) * 32;
    #pragma unroll
    for (int r = 0; r < 4; ++r) {
        atomicAdd(dst + (size_t)r * 32 + l15,      acc0[r]);
        atomicAdd(dst + (size_t)r * 32 + 16 + l15, acc1[r]);
    }
}

// ---------------- reduce1: avw = relu(bn1(av @ w1^T + b1)) -> awts[bh][64][N] bf16 ----------------
__global__ __launch_bounds__(256) void k_red1(const float* __restrict__ av_acc,
    const float* __restrict__ w1, const float* __restrict__ b1,
    const float* __restrict__ g1, const float* __restrict__ be1,
    const float* __restrict__ rm1, const float* __restrict__ rv1,
    bf16* __restrict__ awts)
{
    __shared__ float avl[64 * 33];
    __shared__ float w1l[64 * 33];
    __shared__ float sc[64], sh[64], bb[64];
    int n0 = blockIdx.x * 64, bh = blockIdx.y, h = bh & 3;
    int tid = threadIdx.x;
    const float* ap = av_acc + ((size_t)bh * NN + n0) * 32;
    for (int i = tid; i < 2048; i += 256) {
        avl[(i >> 5) * 33 + (i & 31)] = ap[i];
        w1l[(i >> 5) * 33 + (i & 31)] = w1[i];
    }
    if (tid < 64) {
        int ch = h * 64 + tid;
        float s = g1[ch] * rsqrtf(rv1[ch] + 1e-5f);
        sc[tid] = s; sh[tid] = be1[ch] - rm1[ch] * s; bb[tid] = b1[tid];
    }
    __syncthreads();
    int nb = (tid & 15) * 4, eb = (tid >> 4) * 4;
    float s[4][4];
    #pragma unroll
    for (int i = 0; i < 4; ++i)
        #pragma unroll
        for (int j = 0; j < 4; ++j) s[i][j] = bb[eb + j];
    for (int d = 0; d < 32; ++d) {
        float a0 = avl[(nb+0)*33+d], a1 = avl[(nb+1)*33+d], a2 = avl[(nb+2)*33+d], a3 = avl[(nb+3)*33+d];
        float w0 = w1l[(eb+0)*33+d], w1v = w1l[(eb+1)*33+d], w2v = w1l[(eb+2)*33+d], w3 = w1l[(eb+3)*33+d];
        s[0][0]+=a0*w0; s[0][1]+=a0*w1v; s[0][2]+=a0*w2v; s[0][3]+=a0*w3;
        s[1][0]+=a1*w0; s[1][1]+=a1*w1v; s[1][2]+=a1*w2v; s[1][3]+=a1*w3;
        s[2][0]+=a2*w0; s[2][1]+=a2*w1v; s[2][2]+=a2*w2v; s[2][3]+=a2*w3;
        s[3][0]+=a3*w0; s[3][1]+=a3*w1v; s[3][2]+=a3*w2v; s[3][3]+=a3*w3;
    }
    #pragma unroll
    for (int j = 0; j < 4; ++j) {
        int e = eb + j;
        ushort4 pk;
        float v0 = fmaxf(s[0][j] * sc[e] + sh[e], 0.f);
        float v1 = fmaxf(s[1][j] * sc[e] + sh[e], 0.f);
        float v2 = fmaxf(s[2][j] * sc[e] + sh[e], 0.f);
        float v3 = fmaxf(s[3][j] * sc[e] + sh[e], 0.f);
        bf16 b0 = f2b(v0), b1b = f2b(v1), b2b = f2b(v2), b3 = f2b(v3);
        pk.x = *(unsigned short*)&b0; pk.y = *(unsigned short*)&b1b;
        pk.z = *(unsigned short*)&b2b; pk.w = *(unsigned short*)&b3;
        *reinterpret_cast<ushort4*>(awts + ((size_t)bh * 64 + e) * NN + n0 + nb) = pk;
    }
}

// ---------------- av2 partial: split-K over m, barrier-free, atomic f32 ----------------
__global__ __launch_bounds__(256) void k_av2(const bf16* __restrict__ kt,
    const bf16* __restrict__ qt, const float* __restrict__ rden,
    const bf16* __restrict__ awts, float* __restrict__ av2_acc)
{
    __shared__ __align__(16) bf16 p_lds[2][64 * 72];
    int bh = blockIdx.z;
    int n0 = blockIdx.x * 64;
    int ms = blockIdx.y * MCH;
    int tid = threadIdx.x;
    int w = tid >> 6, lane = tid & 63, l15 = lane & 15, lhi = lane >> 4;
    const float* rdp = rden + (size_t)bh * NN;

    bfrag ak = *reinterpret_cast<const bfrag*>(kt + ((size_t)bh * NN + n0 + w * 16 + l15) * 32 + lhi * 8);
    f32x4 acc[4];
    #pragma unroll
    for (int et = 0; et < 4; ++et) { acc[et][0]=0.f; acc[et][1]=0.f; acc[et][2]=0.f; acc[et][3]=0.f; }
    int rowb = w * 16 + lhi * 4;

    for (int mb = ms; mb < ms + MCH; mb += 64) {
        bf16* pb = p_lds[(mb >> 6) & 1];
        #pragma unroll
        for (int t = 0; t < 4; ++t) {
            bfrag qb = *reinterpret_cast<const bfrag*>(qt + ((size_t)bh * NN + mb + 16 * t + l15) * 32 + lhi * 8);
            f32x4 d = {0.f,0.f,0.f,0.f};
            d = MFMA(ak, qb, d);
            float rd = rdp[mb + 16 * t + l15];
            int colb = 16 * t + l15;
            pb[(rowb + 0) * 72 + colb] = f2b(__expf(d[0]) * rd);
            pb[(rowb + 1) * 72 + colb] = f2b(__expf(d[1]) * rd);
            pb[(rowb + 2) * 72 + colb] = f2b(__expf(d[2]) * rd);
            pb[(rowb + 3) * 72 + colb] = f2b(__expf(d[3]) * rd);
        }
        // wave-private P rows: no barrier needed
        #pragma unroll
        for (int s = 0; s < 2; ++s) {
            bfrag ap = *reinterpret_cast<const bfrag*>(&pb[(w * 16 + l15) * 72 + s * 32 + lhi * 8]);
            #pragma unroll
            for (int et = 0; et < 4; ++et) {
                bfrag ab = *reinterpret_cast<const bfrag*>(awts + ((size_t)bh * 64 + et * 16 + l15) * NN + mb + s * 32 + lhi * 8);
                acc[et] = MFMA(ap, ab, acc[et]);
            }
        }
    }
    float* dst = av2_acc + ((size_t)bh * NN + n0 + rowb) * 64;
    #pragma unroll
    for (int et = 0; et < 4; ++et)
        #pragma unroll
        for (int r = 0; r < 4; ++r)
            atomicAdd(dst + (size_t)r * 64 + et * 16 + l15, acc[et][r]);
}

// ---------------- reduce2: avw2 = relu(bn2(av2 @ w2^T + b2)) -> y[b][256][N] bf16 ----------------
__global__ __launch_bounds__(256) void k_red2(const float* __restrict__ av2_acc,
    const float* __restrict__ w2, const float* __restrict__ b2,
    const float* __restrict__ g2, const float* __restrict__ be2,
    const float* __restrict__ rm2, const float* __restrict__ rv2,
    bf16* __restrict__ y)
{
    __shared__ float a2l[64 * 65];
    __shared__ float w2l[64 * 65];
    __shared__ float sc[64], sh[64], bb[64];
    int n0 = blockIdx.x * 64, bh = blockIdx.y, h = bh & 3, b = bh >> 2;
    int tid = threadIdx.x;
    const float* ap = av2_acc + ((size_t)bh * NN + n0) * 64;
    for (int i = tid; i < 4096; i += 256) {
        a2l[(i >> 6) * 65 + (i & 63)] = ap[i];
        w2l[(i >> 6) * 65 + (i & 63)] = w2[i];
    }
    if (tid < 64) {
        int ch = h * 64 + tid;
        float s = g2[ch] * rsqrtf(rv2[ch] + 1e-5f);
        sc[tid] = s; sh[tid] = be2[ch] - rm2[ch] * s; bb[tid] = b2[tid];
    }
    __syncthreads();
    int nb = (tid & 15) * 4, eb = (tid >> 4) * 4;
    float s[4][4];
    #pragma unroll
    for (int i = 0; i < 4; ++i)
        #pragma unroll
        for (int j = 0; j < 4; ++j) s[i][j] = bb[eb + j];
    for (int d = 0; d < 64; ++d) {
        float a0 = a2l[(nb+0)*65+d], a1 = a2l[(nb+1)*65+d], a2 = a2l[(nb+2)*65+d], a3 = a2l[(nb+3)*65+d];
        float w0 = w2l[(eb+0)*65+d], w1v = w2l[(eb+1)*65+d], w2v = w2l[(eb+2)*65+d], w3 = w2l[(eb+3)*65+d];
        s[0][0]+=a0*w0; s[0][1]+=a0*w1v; s[0][2]+=a0*w2v; s[0][3]+=a0*w3;
        s[1][0]+=a1*w0; s[1][1]+=a1*w1v; s[1][2]+=a1*w2v; s[1][3]+=a1*w3;
        s[2][0]+=a2*w0; s[2][1]+=a2*w1v; s[2][2]+=a2*w2v; s[2][3]+=a2*w3;
        s[3][0]+=a3*w0; s[3][1]+=a3*w1v; s[3][2]+=a3*w2v; s[3][3]+=a3*w3;
    }
    #pragma unroll
    for (int j = 0; j < 4; ++j) {
        int e = eb + j;
        ushort4 pk;
        float v0 = fmaxf(s[0][j] * sc[e] + sh[e], 0.f);
        float v1 = fmaxf(s[1][j] * sc[e] + sh[e], 0.f);
        float v2 = fmaxf(s[2][j] * sc[e] + sh[e], 0.f);
        float v3 = fmaxf(s[3][j] * sc[e] + sh[e], 0.f);
        bf16 b0 = f2b(v0), b1b = f2b(v1), b2b = f2b(v2), b3 = f2b(v3);
        pk.x = *(unsigned short*)&b0; pk.y = *(unsigned short*)&b1b;
        pk.z = *(unsigned short*)&b2b; pk.w = *(unsigned short*)&b3;
        *reinterpret_cast<ushort4*>(y + ((size_t)b * 256 + h * 64 + e) * NN + n0 + nb) = pk;
    }
}

// ---------------- final 1x1 conv (f32 out), 2 n per thread ----------------
__global__ __launch_bounds__(256) void k_final(const bf16* __restrict__ y,
    const float* __restrict__ wf, const float* __restrict__ bf_,
    float* __restrict__ out)
{
    int t = blockIdx.x * 256 + threadIdx.x;
    int n = t * 2;
    if (n >= NN) return;
    int o = blockIdx.y;
    int b = blockIdx.z;
    float s0 = bf_[o], s1 = s0;
    const bf16* yp = y + (size_t)b * 256 * NN + n;
    const float* wp = wf + o * 256;
    #pragma unroll 8
    for (int k = 0; k < 256; ++k) {
        unsigned u = *reinterpret_cast<const unsigned*>(yp + (size_t)k * NN);
        float lo = __uint_as_float(u << 16);
        float hi = __uint_as_float(u & 0xffff0000u);
        s0 += wp[k] * lo;
        s1 += wp[k] * hi;
    }
    float* op = out + ((size_t)b * 64 + o) * NN + n;
    op[0] = s0;
    op[1] = s1;
}

extern "C" void kernel_launch(void* const* d_in, const int* in_sizes, int n_in,
                              void* d_out, int out_size, void* d_ws, size_t ws_size,
                              hipStream_t stream)
{
    const float* x   = (const float*)d_in[0];
    const float* wk  = (const float*)d_in[1];
    const float* bk  = (const float*)d_in[2];
    const float* wq  = (const float*)d_in[3];
    const float* bq  = (const float*)d_in[4];
    const float* wv  = (const float*)d_in[5];
    const float* bv  = (const float*)d_in[6];
    const float* w1  = (const float*)d_in[7];
    const float* b1  = (const float*)d_in[8];
    const float* g1  = (const float*)d_in[9];
    const float* be1 = (const float*)d_in[10];
    const float* rm1 = (const float*)d_in[11];
    const float* rv1 = (const float*)d_in[12];
    const float* w2  = (const float*)d_in[13];
    const float* b2  = (const float*)d_in[14];
    const float* g2  = (const float*)d_in[15];
    const float* be2 = (const float*)d_in[16];
    const float* rm2 = (const float*)d_in[17];
    const float* rv2 = (const float*)d_in[18];
    const float* wf  = (const float*)d_in[19];
    const float* bff = (const float*)d_in[20];
    float* out = (float*)d_out;

    char* ws = (char*)d_ws;
    bf16* kt   = (bf16*)ws;                        // 802816
    bf16* qt   = kt + (size_t)NBH * NN * 32;       // 802816
    bf16* vt   = qt + (size_t)NBH * NN * 32;       // 802816
    bf16* awts = vt + (size_t)NBH * 32 * NN;       // 1605632
    bf16* y    = awts + (size_t)NBH * 64 * NN;     // 1605632
    float* den     = (float*)(y + (size_t)2 * 256 * NN);  // 25088
    float* av_acc  = den + (size_t)NBH * NN;              // 802816
    float* av2_acc = av_acc + (size_t)NBH * NN * 32;      // 1605632
    // zero region: den..av2_acc end = 2433536 f32 = 608384 float4

    k_zero <<<dim3(2377),     256, 0, stream>>>(den, 608384);
    k_proj <<<dim3(49, 2, 4), 256, 0, stream>>>(x, wk, bk, wq, bq, wv, bv, kt, qt, vt);
    k_stats<<<dim3(49, 7, 8), 256, 0, stream>>>(kt, qt, den);
    k_recip<<<dim3(98),       256, 0, stream>>>(den);
    k_av   <<<dim3(49, 7, 8), 256, 0, stream>>>(kt, qt, vt, den, av_acc);
    k_red1 <<<dim3(49, 8),    256, 0, stream>>>(av_acc, w1, b1, g1, be1, rm1, rv1, awts);
    k_av2  <<<dim3(49, 7, 8), 256, 0, stream>>>(kt, qt, den, awts, av2_acc);
    k_red2 <<<dim3(49, 8),    256, 0, stream>>>(av2_acc, w2, b2, g2, be2, rm2, rv2, y);
    k_final<<<dim3(7, 64, 2), 256, 0, stream>>>(y, wf, bff, out);
}